// Round 2
// 370.610 us; speedup vs baseline: 1.0018x; 1.0018x over previous
//
#include <hip/hip_runtime.h>
#include <hip/hip_bf16.h>

// Problem constants (match setup_inputs): B=8, F=64, E=50000, Cout=128, K=5
#define NB 8
#define NF 64
#define NE 50000
#define NO 128
#define NK 320             // K' = 5*64 combined contraction dim
#define CONV_GRID 512      // persistent blocks: exactly 2 resident per CU

typedef short short8 __attribute__((ext_vector_type(8)));
typedef float f32x4 __attribute__((ext_vector_type(4)));

__device__ __forceinline__ unsigned short f2bf(float x) {
    // round-to-nearest-even bf16 conversion (bit trick; matches hardware cvt)
    union { float f; unsigned int u; } v; v.f = x;
    unsigned int r = v.u + 0x7fffu + ((v.u >> 16) & 1u);
    return (unsigned short)(r >> 16);
}
__device__ __forceinline__ float bf2f(unsigned short h) {
    union { unsigned int u; float f; } v; v.u = ((unsigned int)h) << 16; return v.f;
}

// ---------------------------------------------------------------------------
// Kernel 1: transpose x (B,F,E) fp32 -> xT (B,E,F) bf16 (contiguous gathers).
// ---------------------------------------------------------------------------
__global__ __launch_bounds__(256) void transpose_x(
    const float* __restrict__ x, unsigned short* __restrict__ xT, int E)
{
    __shared__ float tile[64][65];  // +1 pad: conflict-free transpose
    int ntiles = (E + 63) >> 6;
    int b = blockIdx.x / ntiles;
    int t = blockIdx.x % ntiles;
    int e0 = t << 6;
    int le = threadIdx.x & 63;
    int q  = threadIdx.x >> 6;     // 0..3
    const float* xb = x + (size_t)b * NF * E;
    #pragma unroll
    for (int i = 0; i < 16; ++i) {
        int f = q * 16 + i;
        int e = e0 + le;
        tile[f][le] = (e < E) ? xb[(size_t)f * E + e] : 0.0f;
    }
    __syncthreads();
    unsigned short* xTb = xT + (size_t)b * E * NF;
    int fp = (threadIdx.x & 31) * 2;   // even f
    int es = threadIdx.x >> 5;         // 0..7
    #pragma unroll
    for (int i = 0; i < 8; ++i) {
        int el = i * 8 + es;
        int e = e0 + el;
        if (e < E) {
            unsigned int pk = (unsigned int)f2bf(tile[fp][el])
                            | ((unsigned int)f2bf(tile[fp + 1][el]) << 16);
            *(unsigned int*)&xTb[(size_t)e * NF + fp] = pk;
        }
    }
}

// ---------------------------------------------------------------------------
// Kernel 2: repack W (Cout,F,1,K) fp32 -> Wt bf16 in MFMA frag order:
//   K' = kp*64 + f ; layout Wt[kblk=K'/8][o=128][slot=K'%8]
// ---------------------------------------------------------------------------
__global__ __launch_bounds__(256) void prep_w(
    const float* __restrict__ W, unsigned short* __restrict__ Wt)
{
    int idx = blockIdx.x * 256 + threadIdx.x;   // 320*128 = 40960 total
    if (idx >= NK * NO) return;
    int K = idx >> 7;       // 0..319
    int o = idx & 127;
    int f  = K & 63;
    int kp = K >> 6;
    float v = W[(size_t)o * (NF * 5) + f * 5 + kp];
    Wt[((size_t)(K >> 3) * NO + o) * 8 + (K & 7)] = f2bf(v);
}

// ---------------------------------------------------------------------------
// Kernel 3: persistent fused gather + combine + MFMA, software-pipelined.
// Grid = 512 blocks x 256 threads (4 waves) = 2 blocks/CU resident.
// Pipeline (T14 async-stage): gathers for unit u+1 are ISSUED into registers
// right after the barrier that publishes Gs(u), so their ~700cy L3 latency
// hides under unit u's MFMA + stores. gemm index vectors are staged 2 ahead.
// MFMA operands are SWAPPED vs the previous version: A = G-frag (rows = e),
// B = W-frag (cols = o); the C layout (col=lane&15, row=(lane>>4)*4+reg)
// then gives each lane 4 CONSECUTIVE e per acc reg -> dwordx4 stores.
// ---------------------------------------------------------------------------
__global__ __launch_bounds__(256, 2) void conv_main(
    const unsigned short* __restrict__ xT,   // (B,E,64) bf16
    const int* __restrict__ gemm,            // (B,E,4) int32
    const unsigned short* __restrict__ Wt,   // [40][128][8] bf16
    const float* __restrict__ bias,
    float* __restrict__ out,                 // (B,128,E) fp32
    int E)
{
    __shared__ __align__(16) unsigned short Gs[40 * 64 * 8]; // 40 KB

    int tid  = threadIdx.x;
    int wave = tid >> 6;
    int lane = tid & 63;
    int l16  = lane & 15;
    int lq   = lane >> 4;           // 0..3

    // ---- persistent per-wave state: W frags + bias (loaded once) ----
    short8 wfrag[10][2];
    #pragma unroll
    for (int ks = 0; ks < 10; ++ks)
        #pragma unroll
        for (int ot = 0; ot < 2; ++ot) {
            int o = (wave * 2 + ot) * 16 + l16;
            wfrag[ks][ot] = *(const short8*)&Wt[((size_t)(ks * 4 + lq) * NO + o) * 8];
        }
    float biasv[2];
    #pragma unroll
    for (int ot = 0; ot < 2; ++ot)
        biasv[ot] = bias[(wave * 2 + ot) * 16 + l16];

    int ntiles = (E + 63) >> 6;
    int nunits = NB * ntiles;
    int ge = tid >> 2;              // 0..63 : e within tile (gather/combine role)
    int j  = tid & 3;               // f-quarter
    int step = gridDim.x;

    if (blockIdx.x >= nunits) return;

    // ---- pipeline registers ----
    uint4 craw[2][5];   // staged gather rows for the unit about to be combined
    int4  gvn;          // gemm indices for the NEXT unit to stage

    // ---- prologue: stage unit u0; prefetch gemm for u0+step ----
    {
        int u = blockIdx.x;
        int b = u / ntiles, et = u % ntiles;
        int e = et * 64 + ge; int eC = (e < E) ? e : (E - 1);
        int4 gv = *(const int4*)(gemm + ((size_t)b * E + eC) * 4);
        const unsigned short* xb = xT + (size_t)b * E * NF;
        int gi[5]; gi[0] = eC; gi[1] = gv.x; gi[2] = gv.y; gi[3] = gv.z; gi[4] = gv.w;
        #pragma unroll
        for (int half = 0; half < 2; ++half) {
            int f0 = half * 32 + j * 8;
            #pragma unroll
            for (int k = 0; k < 5; ++k)
                craw[half][k] = *(const uint4*)&xb[(size_t)gi[k] * NF + f0];
        }
        int un = u + step; if (un > nunits - 1) un = nunits - 1;
        int bn = un / ntiles, etn = un % ntiles;
        int en = etn * 64 + ge; int eCn = (en < E) ? en : (E - 1);
        gvn = *(const int4*)(gemm + ((size_t)bn * E + eCn) * 4);
    }

    for (int u = blockIdx.x; u < nunits; u += step) {
        int b = u / ntiles, etile = u % ntiles;

        // ---- combine staged registers -> bf16 G in LDS ----
        #pragma unroll
        for (int half = 0; half < 2; ++half) {
            const unsigned short* c1 = (const unsigned short*)&craw[half][1];
            const unsigned short* c2 = (const unsigned short*)&craw[half][2];
            const unsigned short* c3 = (const unsigned short*)&craw[half][3];
            const unsigned short* c4 = (const unsigned short*)&craw[half][4];
            uint4 pk[5];
            pk[0] = craw[half][0];                 // x0 passthrough
            unsigned short gb[4][8];
            #pragma unroll
            for (int i = 0; i < 8; ++i) {
                float a1 = bf2f(c1[i]), a2 = bf2f(c2[i]);
                float a3 = bf2f(c3[i]), a4 = bf2f(c4[i]);
                gb[0][i] = f2bf(a1 + a3);
                gb[1][i] = f2bf(a2 + a4);
                gb[2][i] = f2bf(fabsf(a1 - a3));
                gb[3][i] = f2bf(fabsf(a2 - a4));
            }
            pk[1] = *(uint4*)&gb[0][0];
            pk[2] = *(uint4*)&gb[1][0];
            pk[3] = *(uint4*)&gb[2][0];
            pk[4] = *(uint4*)&gb[3][0];
            #pragma unroll
            for (int kp = 0; kp < 5; ++kp) {
                int kblk = kp * 8 + half * 4 + j;   // K-block 0..39
                *(uint4*)&Gs[((size_t)kblk * 64 + ge) * 8] = pk[kp];
            }
        }
        __syncthreads();

        // ---- issue next unit's gathers (latency hidden under MFMA below) ----
        {
            int un = u + step; if (un > nunits - 1) un = nunits - 1;
            int bn = un / ntiles, etn = un % ntiles;
            const unsigned short* xbn = xT + (size_t)bn * E * NF;
            int en = etn * 64 + ge; int eCn = (en < E) ? en : (E - 1);
            int gi[5]; gi[0] = eCn; gi[1] = gvn.x; gi[2] = gvn.y; gi[3] = gvn.z; gi[4] = gvn.w;
            #pragma unroll
            for (int half = 0; half < 2; ++half) {
                int f0 = half * 32 + j * 8;
                #pragma unroll
                for (int k = 0; k < 5; ++k)
                    craw[half][k] = *(const uint4*)&xbn[(size_t)gi[k] * NF + f0];
            }
            int un2 = un + step; if (un2 > nunits - 1) un2 = nunits - 1;
            int bn2 = un2 / ntiles, etn2 = un2 % ntiles;
            int en2 = etn2 * 64 + ge; int eC2 = (en2 < E) ? en2 : (E - 1);
            gvn = *(const int4*)(gemm + ((size_t)bn2 * E + eC2) * 4);
        }

        // ---- Phase B: MFMA, swapped operands (rows = e, cols = o) ----
        f32x4 acc[4][2];
        #pragma unroll
        for (int et = 0; et < 4; ++et)
            #pragma unroll
            for (int ot = 0; ot < 2; ++ot)
                acc[et][ot] = (f32x4){0.f, 0.f, 0.f, 0.f};

        #pragma unroll
        for (int ks = 0; ks < 10; ++ks) {
            short8 bb[4];
            #pragma unroll
            for (int et = 0; et < 4; ++et)
                bb[et] = *(const short8*)&Gs[(((size_t)(ks * 4 + lq)) * 64 + et * 16 + l16) * 8];
            #pragma unroll
            for (int et = 0; et < 4; ++et)
                #pragma unroll
                for (int ot = 0; ot < 2; ++ot)
                    acc[et][ot] = __builtin_amdgcn_mfma_f32_16x16x32_bf16(
                        bb[et], wfrag[ks][ot], acc[et][ot], 0, 0, 0);
        }

        // ---- epilogue: C layout col(o)=lane&15, row(e)=(lane>>4)*4+reg ----
        // Each lane's 4 acc regs are 4 CONSECUTIVE e -> dwordx4 stores.
        // E % 4 == 0 and eb % 4 == 0, so a 4-wide store is all-valid or all-invalid.
        int e0 = etile * 64;
        #pragma unroll
        for (int et = 0; et < 4; ++et) {
            int eb = e0 + et * 16 + lq * 4;
            if (eb < E) {
                #pragma unroll
                for (int ot = 0; ot < 2; ++ot) {
                    int o = (wave * 2 + ot) * 16 + l16;
                    f32x4 v = acc[et][ot];
                    float bv = biasv[ot];
                    v[0] += bv; v[1] += bv; v[2] += bv; v[3] += bv;
                    *(f32x4*)&out[((size_t)b * NO + o) * E + eb] = v;
                }
            }
        }
        __syncthreads();   // protect Gs before next iteration's combine
    }
}

extern "C" void kernel_launch(void* const* d_in, const int* in_sizes, int n_in,
                              void* d_out, int out_size, void* d_ws, size_t ws_size,
                              hipStream_t stream)
{
    const float* x    = (const float*)d_in[0];
    const int*   gemm = (const int*)d_in[1];
    const float* W    = (const float*)d_in[2];
    const float* bias = (const float*)d_in[3];
    float* out = (float*)d_out;

    const int E = NE;
    unsigned short* Wt = (unsigned short*)d_ws;            // 81,920 B
    unsigned short* xT = (unsigned short*)((char*)d_ws + 131072); // bf16, 51.2 MB

    prep_w<<<(NK * NO + 255) / 256, 256, 0, stream>>>(W, Wt);

    int ntiles = (E + 63) / 64;   // 782
    transpose_x<<<NB * ntiles, 256, 0, stream>>>(x, xT, E);

    conv_main<<<CONV_GRID, 256, 0, stream>>>(xT, gemm, Wt, bias, out, E);
}